// Round 6
// baseline (677.749 us; speedup 1.0000x reference)
//
#include <hip/hip_runtime.h>

// Fused: 1x1(64->384, MFMA fp16) -> dw3x3 (fp32) -> per-8x8-patch circular
//        conv(q,k) (fdot2, fp32 acc) -> channel LN (shfl) -> fused dw+gate
//        -> 1x1(128->64, MFMA fp16)
// One workgroup per (batch, 8x8 patch). 512 threads. LDS 54272 B -> 3 blocks/CU
// (VGPR capped <=85 via __launch_bounds__(512,6)). 13 barriers total.

typedef _Float16 f16x8 __attribute__((ext_vector_type(8)));
typedef _Float16 f16x4 __attribute__((ext_vector_type(4)));
typedef _Float16 f16x2 __attribute__((ext_vector_type(2)));
typedef __fp16   h16x2 __attribute__((ext_vector_type(2)));   // fdot2 ABI type
typedef float    f32x4 __attribute__((ext_vector_type(4)));

// LDS byte offsets
#define XS_OFF    0       // f16[112][64] x tile, XOR-swizzled 8-elem chunks
#define HS_OFF    14336   // f16[64][100] hidden chunk on 10x10 tile
#define QCC_OFF   27136   // f16[128][68] q patch; cc overwrites in place
#define TMP_OFF   44544   // f16[64][68] k chunk [ch][pix]; gs[pix][ch] alias kc>=4
#define MU_OFF    53248   // f32[64]
#define RSTD_OFF  53504   // f32[64]
#define LNW_OFF   53760   // f16[128]
#define LNB_OFF   54016   // f16[128]
#define LDS_BYTES 54272

__global__ __launch_bounds__(512, 6) void lfsa_fused(
    const float* __restrict__ x,
    const float* __restrict__ wh,
    const float* __restrict__ wdw,
    const float* __restrict__ nw,
    const float* __restrict__ nb,
    const float* __restrict__ wo,
    float* __restrict__ out)
{
    extern __shared__ char lds[];
    _Float16* xs    = (_Float16*)(lds + XS_OFF);
    _Float16* hs    = (_Float16*)(lds + HS_OFF);
    _Float16* qcc16 = (_Float16*)(lds + QCC_OFF);
    _Float16* tmp16 = (_Float16*)(lds + TMP_OFF);   // k chunks [ch][68]
    _Float16* gs16  = (_Float16*)(lds + TMP_OFF);   // gated v  [pix][68]
    float*    mu_s  = (float*)(lds + MU_OFF);
    float*    rstd_s= (float*)(lds + RSTD_OFF);
    _Float16* lnw16 = (_Float16*)(lds + LNW_OFF);
    _Float16* lnb16 = (_Float16*)(lds + LNB_OFF);

    const int tid = threadIdx.x;
    const int px = blockIdx.x, py = blockIdx.y, bz = blockIdx.z;
    const int lane = tid & 63;
    const int wv   = tid >> 6;     // wave 0..7
    const int m16  = lane & 15;
    const int quad = lane >> 4;

    // ---- stage x tile (10x10 + zero halo) into swizzled xs fp16 ----
    {
        const int pix  = tid & 127;
        const int gg   = tid >> 7;            // 0..3 -> channels gg*16..+15
        const int prow = pix / 10;
        const int pcol = pix - prow * 10;
        const int yy = py * 8 + prow - 1;
        const int xx = px * 8 + pcol - 1;
        const bool inimg = (pix < 100) && ((unsigned)yy < 256u) && ((unsigned)xx < 256u);
        if (pix < 112) {
            const float* xp = inimg
                ? (x + (size_t)((bz * 64 + gg * 16) * 65536 + yy * 256 + xx)) : x;
            f16x8 lo, hi;
            #pragma unroll
            for (int i = 0; i < 8; ++i) {
                lo[i] = (_Float16)(inimg ? xp[(size_t)i * 65536] : 0.0f);
                hi[i] = (_Float16)(inimg ? xp[(size_t)(i + 8) * 65536] : 0.0f);
            }
            const int s = pix & 7;
            _Float16* xrow = xs + pix * 64;
            *(f16x8*)(xrow + (((2 * gg)     ^ s) * 8)) = lo;
            *(f16x8*)(xrow + (((2 * gg + 1) ^ s) * 8)) = hi;
        }
        if (tid < 128) { lnw16[tid] = (_Float16)nw[tid]; lnb16[tid] = (_Float16)nb[tid]; }
    }

    // per-phase mappings
    const int dwo = tid >> 3;          // dw / circ: channel-in-chunk 0..63
    const int blk = tid & 7;           // dw: block (row-strip kc<4, col-strip kc>=4)
    const int by2 = (blk >> 1) * 2;
    const int bx4 = (blk & 1) * 4;
    const int ci  = tid & 7;           // circ: output row

    // ---- weight prefetch registers ----
    const int ot = wv >> 1;            // GEMM1 o-tile 0..3
    const float* wha = wh + (size_t)(ot * 16 + m16) * 64 + quad * 8;
    float4 wr0 = *(const float4*)(wha);
    float4 wr1 = *(const float4*)(wha + 4);
    float4 wr2 = *(const float4*)(wha + 32);
    float4 wr3 = *(const float4*)(wha + 36);
    float w9n[9];
    #pragma unroll
    for (int t = 0; t < 9; ++t) w9n[t] = wdw[dwo * 9 + t];
    float4 wo0, wo1, wo2, wo3;         // wo frags, loaded at kc==3 / kc==4

    f32x4 pacc2[2] = {{0.f,0.f,0.f,0.f},{0.f,0.f,0.f,0.f}};

    __syncthreads();

    #pragma unroll 1
    for (int kc = 0; kc < 6; ++kc) {
        // ---- materialize current weights, issue next-kc prefetch ----
        const f16x8 a0 = {(_Float16)wr0.x,(_Float16)wr0.y,(_Float16)wr0.z,(_Float16)wr0.w,
                          (_Float16)wr1.x,(_Float16)wr1.y,(_Float16)wr1.z,(_Float16)wr1.w};
        const f16x8 a1 = {(_Float16)wr2.x,(_Float16)wr2.y,(_Float16)wr2.z,(_Float16)wr2.w,
                          (_Float16)wr3.x,(_Float16)wr3.y,(_Float16)wr3.z,(_Float16)wr3.w};
        float w9c[9];
        #pragma unroll
        for (int t = 0; t < 9; ++t) w9c[t] = w9n[t];
        if (kc < 5) {
            const float* nx = wha + (size_t)(kc + 1) * 4096;
            wr0 = *(const float4*)(nx);
            wr1 = *(const float4*)(nx + 4);
            wr2 = *(const float4*)(nx + 32);
            wr3 = *(const float4*)(nx + 36);
            #pragma unroll
            for (int t = 0; t < 9; ++t) w9n[t] = wdw[(kc + 1) * 576 + dwo * 9 + t];
        }
        if (kc == 3) {
            const float* wop = wo + (size_t)(ot * 16 + m16) * 128 + quad * 8;
            wo0 = *(const float4*)(wop);
            wo1 = *(const float4*)(wop + 4);
            wo2 = *(const float4*)(wop + 32);
            wo3 = *(const float4*)(wop + 36);
        }

        // ---- 1x1 conv GEMM chunk via MFMA -> hs (fp16) ----
        {
            const int np  = (wv & 1) ? 3 : 4;
            const int pt0 = (wv & 1) * 4;
            for (int pp = 0; pp < np; ++pp) {
                const int pt = pt0 + pp;
                const int pixg = pt * 16 + m16;
                const _Float16* xrow = xs + pixg * 64;
                const int c0 = ((quad ^ (pixg & 7)) * 8);
                const f16x8 b0 = *(const f16x8*)(xrow + c0);
                const f16x8 b1 = *(const f16x8*)(xrow + (c0 ^ 32));
                f32x4 d = {0.f,0.f,0.f,0.f};
                d = __builtin_amdgcn_mfma_f32_16x16x32_f16(a0, b0, d, 0, 0, 0);
                d = __builtin_amdgcn_mfma_f32_16x16x32_f16(a1, b1, d, 0, 0, 0);
                if (pixg < 100) {
                    const int oloc = ot * 16 + quad * 4;
                    #pragma unroll
                    for (int r = 0; r < 4; ++r)
                        hs[100 * (oloc + r) + pixg] = (_Float16)d[r];
                }
            }
        }
        __syncthreads();   // B1: hs ready; fences prior-kc LDS consumers

        if (kc < 4) {
            // ---- depthwise 3x3, row-strip 2x4 -> q (kc<2) or k (kc 2,3) ----
            const _Float16* hrow = hs + 100 * dwo;
            float in[4][6];
            #pragma unroll
            for (int r = 0; r < 4; ++r) {
                const _Float16* rp = hrow + (by2 + r) * 10 + bx4;
                const f16x2 p0 = *(const f16x2*)rp;
                const f16x2 p1 = *(const f16x2*)(rp + 2);
                const f16x2 p2 = *(const f16x2*)(rp + 4);
                in[r][0] = (float)p0[0]; in[r][1] = (float)p0[1];
                in[r][2] = (float)p1[0]; in[r][3] = (float)p1[1];
                in[r][4] = (float)p2[0]; in[r][5] = (float)p2[1];
            }
            #pragma unroll
            for (int r = 0; r < 2; ++r) {
                float rv[4];
                #pragma unroll
                for (int c = 0; c < 4; ++c) {
                    float s = 0.0f;
                    #pragma unroll
                    for (int dy = 0; dy < 3; ++dy)
                        #pragma unroll
                        for (int dx = 0; dx < 3; ++dx)
                            s = fmaf(w9c[dy * 3 + dx], in[r + dy][c + dx], s);
                    rv[c] = s;
                }
                const int off = (by2 + r) * 8 + bx4;
                _Float16* dst = (kc < 2) ? (qcc16 + 68 * (kc * 64 + dwo))
                                         : (tmp16 + 68 * dwo);
                *(f16x4*)(dst + off) = f16x4{(_Float16)rv[0], (_Float16)rv[1],
                                             (_Float16)rv[2], (_Float16)rv[3]};
            }
        } else {
            // ---- fused dw3x3 + gate, col-strip -> gs[pix][ch] ----
            const _Float16* hrow = hs + 100 * dwo;
            float c0[10], c1[10], c2[10];
            #pragma unroll
            for (int rr = 0; rr < 10; ++rr) {
                c0[rr] = (float)hrow[rr * 10 + blk];
                c1[rr] = (float)hrow[rr * 10 + blk + 1];
                c2[rr] = (float)hrow[rr * 10 + blk + 2];
            }
            const int chg = (kc - 4) * 64 + dwo;          // 0..127
            const float lw = (float)lnw16[chg], lb = (float)lnb16[chg];
            const _Float16* ccrow = qcc16 + 68 * chg;
            #pragma unroll
            for (int r = 0; r < 8; ++r) {
                float s = 0.0f;
                #pragma unroll
                for (int dy = 0; dy < 3; ++dy) {
                    s = fmaf(w9c[dy * 3 + 0], c0[r + dy], s);
                    s = fmaf(w9c[dy * 3 + 1], c1[r + dy], s);
                    s = fmaf(w9c[dy * 3 + 2], c2[r + dy], s);
                }
                const int p = r * 8 + blk;
                const float nrm = ((float)ccrow[p] - mu_s[p]) * rstd_s[p] * lw + lb;
                gs16[p * 68 + dwo] = (_Float16)(s * nrm);
            }
        }

        if (kc == 2 || kc == 3) {
            // k rows written by this same 8-thread cluster -> in-wave RAW, no bar
            // ---- circular conv via fdot2; cc overwrites q in place (fp16) ----
            const int ch = (kc - 2) * 64 + dwo;
            _Float16* qrow = qcc16 + 68 * ch;
            const _Float16* krow = tmp16 + 68 * dwo;
            float acc[8];
            #pragma unroll
            for (int j = 0; j < 8; ++j) acc[j] = 0.0f;
            #pragma unroll
            for (int a = 0; a < 8; ++a) {
                const f16x8 qv = *(const f16x8*)(qrow + 8 * a);
                h16x2 q2[4];
                #pragma unroll
                for (int t = 0; t < 4; ++t) {
                    q2[t][0] = (__fp16)qv[2 * t];
                    q2[t][1] = (__fp16)qv[2 * t + 1];
                }
                const int r = (ci - a) & 7;
                const f16x8 kr = *(const f16x8*)(krow + 8 * r);
                h16x2 rp[8];
                #pragma unroll
                for (int i = 0; i < 8; ++i)
                    rp[i] = h16x2{(__fp16)kr[i], (__fp16)kr[(i + 7) & 7]};
                #pragma unroll
                for (int j = 0; j < 8; ++j)
                    #pragma unroll
                    for (int t = 0; t < 4; ++t)
                        acc[j] = __builtin_amdgcn_fdot2(q2[t], rp[(j - 2 * t) & 7],
                                                        acc[j], false);
            }
            *(f16x4*)(qrow + 8 * ci)     = f16x4{(_Float16)acc[0], (_Float16)acc[1],
                                                 (_Float16)acc[2], (_Float16)acc[3]};
            *(f16x4*)(qrow + 8 * ci + 4) = f16x4{(_Float16)acc[4], (_Float16)acc[5],
                                                 (_Float16)acc[6], (_Float16)acc[7]};
        }
        __syncthreads();   // B2: dw/circ outputs ready; hs safe for next GEMM

        if (kc == 3) {
            // ---- LN stats (all cc visible after B2); store mu and rstd ----
            const int p = 8 * wv + (lane & 7);
            const int g = lane >> 3;
            float s = 0.0f, s2v = 0.0f;
            #pragma unroll
            for (int i = 0; i < 16; ++i) {
                const float v = (float)qcc16[68 * (g + 8 * i) + p];
                s += v; s2v = fmaf(v, v, s2v);
            }
            #pragma unroll
            for (int m = 8; m < 64; m <<= 1) {
                s   += __shfl_xor(s, m, 64);
                s2v += __shfl_xor(s2v, m, 64);
            }
            if (lane < 8) {
                const float mu = s * (1.0f / 128.0f);
                mu_s[p]   = mu;
                rstd_s[p] = rsqrtf(s2v * (1.0f / 128.0f) - mu * mu + 1e-5f);
            }
            // consumed at kc>=4 after that kc's B1 -> no extra barrier
        }

        if (kc >= 4) {
            // ---- projection MFMA over this 64-ch chunk (gs ready after B2) ----
            const f16x8 pa0 = {(_Float16)wo0.x,(_Float16)wo0.y,(_Float16)wo0.z,(_Float16)wo0.w,
                               (_Float16)wo1.x,(_Float16)wo1.y,(_Float16)wo1.z,(_Float16)wo1.w};
            const f16x8 pa1 = {(_Float16)wo2.x,(_Float16)wo2.y,(_Float16)wo2.z,(_Float16)wo2.w,
                               (_Float16)wo3.x,(_Float16)wo3.y,(_Float16)wo3.z,(_Float16)wo3.w};
            #pragma unroll
            for (int tt = 0; tt < 2; ++tt) {
                const int pt = (wv & 1) * 2 + tt;
                const _Float16* bp = gs16 + (pt * 16 + m16) * 68 + quad * 8;
                const f16x8 b0 = *(const f16x8*)bp;
                const f16x8 b1 = *(const f16x8*)(bp + 32);
                pacc2[tt] = __builtin_amdgcn_mfma_f32_16x16x32_f16(pa0, b0, pacc2[tt], 0, 0, 0);
                pacc2[tt] = __builtin_amdgcn_mfma_f32_16x16x32_f16(pa1, b1, pacc2[tt], 0, 0, 0);
            }
            if (kc == 4) {   // prefetch wo frags for the second 64-ch chunk
                const float* wop = wo + (size_t)(ot * 16 + m16) * 128 + 64 + quad * 8;
                wo0 = *(const float4*)(wop);
                wo1 = *(const float4*)(wop + 4);
                wo2 = *(const float4*)(wop + 32);
                wo3 = *(const float4*)(wop + 36);
            }
            // gs re-written only after next kc's B1 -> proj reads are safe
        }
    }

    // ---- write output: o = ot*16 + quad*4 + reg, pix from C-frag cols ----
    {
        #pragma unroll
        for (int tt = 0; tt < 2; ++tt) {
            const int pixg = ((wv & 1) * 2 + tt) * 16 + m16;   // 0..63
            const int r = pixg >> 3, c = pixg & 7;
            float* op = out + (size_t)(bz * 64 + ot * 16 + quad * 4) * 65536
                            + (py * 8 + r) * 256 + px * 8 + c;
            #pragma unroll
            for (int reg = 0; reg < 4; ++reg)
                op[(size_t)reg * 65536] = pacc2[tt][reg];
        }
    }
}

extern "C" void kernel_launch(void* const* d_in, const int* in_sizes, int n_in,
                              void* d_out, int out_size, void* d_ws, size_t ws_size,
                              hipStream_t stream) {
    const float* x   = (const float*)d_in[0];
    const float* wh  = (const float*)d_in[1];
    const float* wdw = (const float*)d_in[2];
    const float* nw  = (const float*)d_in[3];
    const float* nb  = (const float*)d_in[4];
    const float* wo  = (const float*)d_in[5];
    float* outp = (float*)d_out;

    (void)hipFuncSetAttribute((const void*)lfsa_fused,
                              hipFuncAttributeMaxDynamicSharedMemorySize, LDS_BYTES);
    dim3 grid(32, 32, 4);
    lfsa_fused<<<grid, 512, LDS_BYTES, stream>>>(x, wh, wdw, nw, nb, wo, outp);
}

// Round 7
// 391.298 us; speedup vs baseline: 1.7321x; 1.7321x over previous
//
#include <hip/hip_runtime.h>

// Fused: 1x1(64->384, MFMA fp16) -> dw3x3 (fp32) -> per-8x8-patch circular
//        conv(q,k) (fdot2, fp32 acc) -> channel LN (shfl) -> fused dw+gate
//        -> 1x1(128->64, MFMA fp16)
// One workgroup per (batch, 8x8 patch). 512 threads. LDS 54272 B -> 3 blocks/CU
// if VGPR<=85. launch_bounds(512,4): cap 128, NO spill (the (512,6) cap caused
// 1.1GB/dispatch scratch spill in R6). 13 barriers total.

typedef _Float16 f16x8 __attribute__((ext_vector_type(8)));
typedef _Float16 f16x4 __attribute__((ext_vector_type(4)));
typedef _Float16 f16x2 __attribute__((ext_vector_type(2)));
typedef __fp16   h16x2 __attribute__((ext_vector_type(2)));   // fdot2 ABI type
typedef float    f32x4 __attribute__((ext_vector_type(4)));

// LDS byte offsets
#define XS_OFF    0       // f16[112][64] x tile, XOR-swizzled 8-elem chunks
#define HS_OFF    14336   // f16[64][100] hidden chunk on 10x10 tile
#define QCC_OFF   27136   // f16[128][68] q patch; cc overwrites in place
#define TMP_OFF   44544   // f16[64][68] k chunk [ch][pix]; gs[pix][ch] alias kc>=4
#define MU_OFF    53248   // f32[64]
#define RSTD_OFF  53504   // f32[64]
#define LNW_OFF   53760   // f16[128]
#define LNB_OFF   54016   // f16[128]
#define LDS_BYTES 54272

__global__ __launch_bounds__(512, 4) void lfsa_fused(
    const float* __restrict__ x,
    const float* __restrict__ wh,
    const float* __restrict__ wdw,
    const float* __restrict__ nw,
    const float* __restrict__ nb,
    const float* __restrict__ wo,
    float* __restrict__ out)
{
    extern __shared__ char lds[];
    _Float16* xs    = (_Float16*)(lds + XS_OFF);
    _Float16* hs    = (_Float16*)(lds + HS_OFF);
    _Float16* qcc16 = (_Float16*)(lds + QCC_OFF);
    _Float16* tmp16 = (_Float16*)(lds + TMP_OFF);   // k chunks [ch][68]
    _Float16* gs16  = (_Float16*)(lds + TMP_OFF);   // gated v  [pix][68]
    float*    mu_s  = (float*)(lds + MU_OFF);
    float*    rstd_s= (float*)(lds + RSTD_OFF);
    _Float16* lnw16 = (_Float16*)(lds + LNW_OFF);
    _Float16* lnb16 = (_Float16*)(lds + LNB_OFF);

    const int tid = threadIdx.x;
    const int px = blockIdx.x, py = blockIdx.y, bz = blockIdx.z;
    const int lane = tid & 63;
    const int wv   = tid >> 6;     // wave 0..7
    const int m16  = lane & 15;
    const int quad = lane >> 4;

    // ---- stage x tile (10x10 + zero halo) into swizzled xs fp16 ----
    {
        const int pix  = tid & 127;
        const int gg   = tid >> 7;            // 0..3 -> channels gg*16..+15
        const int prow = pix / 10;
        const int pcol = pix - prow * 10;
        const int yy = py * 8 + prow - 1;
        const int xx = px * 8 + pcol - 1;
        const bool inimg = (pix < 100) && ((unsigned)yy < 256u) && ((unsigned)xx < 256u);
        if (pix < 112) {
            const float* xp = inimg
                ? (x + (size_t)((bz * 64 + gg * 16) * 65536 + yy * 256 + xx)) : x;
            f16x8 lo, hi;
            #pragma unroll
            for (int i = 0; i < 8; ++i) {
                lo[i] = (_Float16)(inimg ? xp[(size_t)i * 65536] : 0.0f);
                hi[i] = (_Float16)(inimg ? xp[(size_t)(i + 8) * 65536] : 0.0f);
            }
            const int s = pix & 7;
            _Float16* xrow = xs + pix * 64;
            *(f16x8*)(xrow + (((2 * gg)     ^ s) * 8)) = lo;
            *(f16x8*)(xrow + (((2 * gg + 1) ^ s) * 8)) = hi;
        }
        if (tid < 128) { lnw16[tid] = (_Float16)nw[tid]; lnb16[tid] = (_Float16)nb[tid]; }
    }

    // per-phase mappings
    const int dwo = tid >> 3;          // dw / circ: channel-in-chunk 0..63
    const int blk = tid & 7;           // dw: block (row-strip kc<4, col-strip kc>=4)
    const int by2 = (blk >> 1) * 2;
    const int bx4 = (blk & 1) * 4;
    const int ci  = tid & 7;           // circ: output row

    // ---- w_hidden prefetch registers (A-frags for GEMM1) ----
    const int ot = wv >> 1;            // GEMM1 o-tile 0..3
    const float* wha = wh + (size_t)(ot * 16 + m16) * 64 + quad * 8;
    float4 wr0 = *(const float4*)(wha);
    float4 wr1 = *(const float4*)(wha + 4);
    float4 wr2 = *(const float4*)(wha + 32);
    float4 wr3 = *(const float4*)(wha + 36);

    f32x4 pacc2[2] = {{0.f,0.f,0.f,0.f},{0.f,0.f,0.f,0.f}};

    __syncthreads();

    #pragma unroll 1
    for (int kc = 0; kc < 6; ++kc) {
        // ---- materialize current A-frags, issue next-kc prefetch ----
        const f16x8 a0 = {(_Float16)wr0.x,(_Float16)wr0.y,(_Float16)wr0.z,(_Float16)wr0.w,
                          (_Float16)wr1.x,(_Float16)wr1.y,(_Float16)wr1.z,(_Float16)wr1.w};
        const f16x8 a1 = {(_Float16)wr2.x,(_Float16)wr2.y,(_Float16)wr2.z,(_Float16)wr2.w,
                          (_Float16)wr3.x,(_Float16)wr3.y,(_Float16)wr3.z,(_Float16)wr3.w};
        if (kc < 5) {
            const float* nx = wha + (size_t)(kc + 1) * 4096;
            wr0 = *(const float4*)(nx);
            wr1 = *(const float4*)(nx + 4);
            wr2 = *(const float4*)(nx + 32);
            wr3 = *(const float4*)(nx + 36);
        }
        // dw taps for THIS kc (L2-hot, 13.8 KB total; latency covered by GEMM+B1)
        float w9c[9];
        #pragma unroll
        for (int t = 0; t < 9; ++t) w9c[t] = wdw[(kc * 64 + dwo) * 9 + t];

        // ---- 1x1 conv GEMM chunk via MFMA -> hs (fp16) ----
        {
            const int np  = (wv & 1) ? 3 : 4;
            const int pt0 = (wv & 1) * 4;
            for (int pp = 0; pp < np; ++pp) {
                const int pt = pt0 + pp;
                const int pixg = pt * 16 + m16;
                const _Float16* xrow = xs + pixg * 64;
                const int c0 = ((quad ^ (pixg & 7)) * 8);
                const f16x8 b0 = *(const f16x8*)(xrow + c0);
                const f16x8 b1 = *(const f16x8*)(xrow + (c0 ^ 32));
                f32x4 d = {0.f,0.f,0.f,0.f};
                d = __builtin_amdgcn_mfma_f32_16x16x32_f16(a0, b0, d, 0, 0, 0);
                d = __builtin_amdgcn_mfma_f32_16x16x32_f16(a1, b1, d, 0, 0, 0);
                if (pixg < 100) {
                    const int oloc = ot * 16 + quad * 4;
                    #pragma unroll
                    for (int r = 0; r < 4; ++r)
                        hs[100 * (oloc + r) + pixg] = (_Float16)d[r];
                }
            }
        }
        __syncthreads();   // B1: hs ready; fences prior-kc LDS consumers

        if (kc < 4) {
            // ---- depthwise 3x3, row-strip 2x4 -> q (kc<2) or k (kc 2,3) ----
            const _Float16* hrow = hs + 100 * dwo;
            float in[4][6];
            #pragma unroll
            for (int r = 0; r < 4; ++r) {
                const _Float16* rp = hrow + (by2 + r) * 10 + bx4;
                const f16x2 p0 = *(const f16x2*)rp;
                const f16x2 p1 = *(const f16x2*)(rp + 2);
                const f16x2 p2 = *(const f16x2*)(rp + 4);
                in[r][0] = (float)p0[0]; in[r][1] = (float)p0[1];
                in[r][2] = (float)p1[0]; in[r][3] = (float)p1[1];
                in[r][4] = (float)p2[0]; in[r][5] = (float)p2[1];
            }
            #pragma unroll
            for (int r = 0; r < 2; ++r) {
                float rv[4];
                #pragma unroll
                for (int c = 0; c < 4; ++c) {
                    float s = 0.0f;
                    #pragma unroll
                    for (int dy = 0; dy < 3; ++dy)
                        #pragma unroll
                        for (int dx = 0; dx < 3; ++dx)
                            s = fmaf(w9c[dy * 3 + dx], in[r + dy][c + dx], s);
                    rv[c] = s;
                }
                const int off = (by2 + r) * 8 + bx4;
                _Float16* dst = (kc < 2) ? (qcc16 + 68 * (kc * 64 + dwo))
                                         : (tmp16 + 68 * dwo);
                *(f16x4*)(dst + off) = f16x4{(_Float16)rv[0], (_Float16)rv[1],
                                             (_Float16)rv[2], (_Float16)rv[3]};
            }
        } else {
            // ---- fused dw3x3 + gate, col-strip, two 4-row halves ----
            const _Float16* hrow = hs + 100 * dwo;
            const int chg = (kc - 4) * 64 + dwo;          // 0..127
            const float lw = (float)lnw16[chg], lb = (float)lnb16[chg];
            const _Float16* ccrow = qcc16 + 68 * chg;
            #pragma unroll
            for (int half = 0; half < 2; ++half) {
                float cA[6], cB[6], cC[6];
                #pragma unroll
                for (int rr = 0; rr < 6; ++rr) {
                    const int row = half * 4 + rr;
                    cA[rr] = (float)hrow[row * 10 + blk];
                    cB[rr] = (float)hrow[row * 10 + blk + 1];
                    cC[rr] = (float)hrow[row * 10 + blk + 2];
                }
                #pragma unroll
                for (int r = 0; r < 4; ++r) {
                    float s = 0.0f;
                    #pragma unroll
                    for (int dy = 0; dy < 3; ++dy) {
                        s = fmaf(w9c[dy * 3 + 0], cA[r + dy], s);
                        s = fmaf(w9c[dy * 3 + 1], cB[r + dy], s);
                        s = fmaf(w9c[dy * 3 + 2], cC[r + dy], s);
                    }
                    const int p = (half * 4 + r) * 8 + blk;
                    const float nrm = ((float)ccrow[p] - mu_s[p]) * rstd_s[p] * lw + lb;
                    gs16[p * 68 + dwo] = (_Float16)(s * nrm);
                }
            }
        }

        if (kc == 2 || kc == 3) {
            // k rows written by this same 8-thread cluster -> in-wave RAW, no bar
            // ---- circular conv via fdot2; cc overwrites q in place (fp16) ----
            const int ch = (kc - 2) * 64 + dwo;
            _Float16* qrow = qcc16 + 68 * ch;
            const _Float16* krow = tmp16 + 68 * dwo;
            float acc[8];
            #pragma unroll
            for (int j = 0; j < 8; ++j) acc[j] = 0.0f;
            #pragma unroll
            for (int a = 0; a < 8; ++a) {
                const f16x8 qv = *(const f16x8*)(qrow + 8 * a);
                h16x2 q2[4];
                #pragma unroll
                for (int t = 0; t < 4; ++t) {
                    q2[t][0] = (__fp16)qv[2 * t];
                    q2[t][1] = (__fp16)qv[2 * t + 1];
                }
                const int r = (ci - a) & 7;
                const f16x8 kr = *(const f16x8*)(krow + 8 * r);
                h16x2 rp[8];
                #pragma unroll
                for (int i = 0; i < 8; ++i)
                    rp[i] = h16x2{(__fp16)kr[i], (__fp16)kr[(i + 7) & 7]};
                #pragma unroll
                for (int j = 0; j < 8; ++j)
                    #pragma unroll
                    for (int t = 0; t < 4; ++t)
                        acc[j] = __builtin_amdgcn_fdot2(q2[t], rp[(j - 2 * t) & 7],
                                                        acc[j], false);
            }
            *(f16x4*)(qrow + 8 * ci)     = f16x4{(_Float16)acc[0], (_Float16)acc[1],
                                                 (_Float16)acc[2], (_Float16)acc[3]};
            *(f16x4*)(qrow + 8 * ci + 4) = f16x4{(_Float16)acc[4], (_Float16)acc[5],
                                                 (_Float16)acc[6], (_Float16)acc[7]};
        }
        __syncthreads();   // B2: dw/circ outputs ready; hs safe for next GEMM

        if (kc == 3) {
            // ---- LN stats (all cc visible after B2); store mu and rstd ----
            const int p = 8 * wv + (lane & 7);
            const int g = lane >> 3;
            float s = 0.0f, s2v = 0.0f;
            #pragma unroll
            for (int i = 0; i < 16; ++i) {
                const float v = (float)qcc16[68 * (g + 8 * i) + p];
                s += v; s2v = fmaf(v, v, s2v);
            }
            #pragma unroll
            for (int m = 8; m < 64; m <<= 1) {
                s   += __shfl_xor(s, m, 64);
                s2v += __shfl_xor(s2v, m, 64);
            }
            if (lane < 8) {
                const float mu = s * (1.0f / 128.0f);
                mu_s[p]   = mu;
                rstd_s[p] = rsqrtf(s2v * (1.0f / 128.0f) - mu * mu + 1e-5f);
            }
            // consumed at kc>=4 after that kc's B1 -> no extra barrier
        }

        if (kc >= 4) {
            // ---- projection MFMA over this 64-ch chunk (gs ready after B2) ----
            const int cb = (kc - 4) * 64;
            const float* wop = wo + (size_t)(ot * 16 + m16) * 128 + cb + quad * 8;
            const float4 u0 = *(const float4*)(wop);
            const float4 u1 = *(const float4*)(wop + 4);
            const float4 u2 = *(const float4*)(wop + 32);
            const float4 u3 = *(const float4*)(wop + 36);
            const f16x8 pa0 = {(_Float16)u0.x,(_Float16)u0.y,(_Float16)u0.z,(_Float16)u0.w,
                               (_Float16)u1.x,(_Float16)u1.y,(_Float16)u1.z,(_Float16)u1.w};
            const f16x8 pa1 = {(_Float16)u2.x,(_Float16)u2.y,(_Float16)u2.z,(_Float16)u2.w,
                               (_Float16)u3.x,(_Float16)u3.y,(_Float16)u3.z,(_Float16)u3.w};
            #pragma unroll
            for (int tt = 0; tt < 2; ++tt) {
                const int pt = (wv & 1) * 2 + tt;
                const _Float16* bp = gs16 + (pt * 16 + m16) * 68 + quad * 8;
                const f16x8 b0 = *(const f16x8*)bp;
                const f16x8 b1 = *(const f16x8*)(bp + 32);
                pacc2[tt] = __builtin_amdgcn_mfma_f32_16x16x32_f16(pa0, b0, pacc2[tt], 0, 0, 0);
                pacc2[tt] = __builtin_amdgcn_mfma_f32_16x16x32_f16(pa1, b1, pacc2[tt], 0, 0, 0);
            }
            // gs re-written only after next kc's B1 -> proj reads are safe
        }
    }

    // ---- write output: o = ot*16 + quad*4 + reg, pix from C-frag cols ----
    {
        #pragma unroll
        for (int tt = 0; tt < 2; ++tt) {
            const int pixg = ((wv & 1) * 2 + tt) * 16 + m16;   // 0..63
            const int r = pixg >> 3, c = pixg & 7;
            float* op = out + (size_t)(bz * 64 + ot * 16 + quad * 4) * 65536
                            + (py * 8 + r) * 256 + px * 8 + c;
            #pragma unroll
            for (int reg = 0; reg < 4; ++reg)
                op[(size_t)reg * 65536] = pacc2[tt][reg];
        }
    }
}

extern "C" void kernel_launch(void* const* d_in, const int* in_sizes, int n_in,
                              void* d_out, int out_size, void* d_ws, size_t ws_size,
                              hipStream_t stream) {
    const float* x   = (const float*)d_in[0];
    const float* wh  = (const float*)d_in[1];
    const float* wdw = (const float*)d_in[2];
    const float* nw  = (const float*)d_in[3];
    const float* nb  = (const float*)d_in[4];
    const float* wo  = (const float*)d_in[5];
    float* outp = (float*)d_out;

    (void)hipFuncSetAttribute((const void*)lfsa_fused,
                              hipFuncAttributeMaxDynamicSharedMemorySize, LDS_BYTES);
    dim3 grid(32, 32, 4);
    lfsa_fused<<<grid, 512, LDS_BYTES, stream>>>(x, wh, wdw, nw, nb, wo, outp);
}